// Round 1
// baseline (1104.662 us; speedup 1.0000x reference)
//
#include <hip/hip_runtime.h>

// SeparateSourceDense: out[n,:] = x[n,:] @ kernel[source[n]] + bias[source[n],:]
// N=8192 rows, F=256, OUT=256, S=16 sources.
// Strategy: bucket rows by source (counting sort), then grouped fp32 GEMM with
// LDS tiling + register micro-tiles. fp32 accumulate (threshold is 9.9e-2,
// fp32 gives ~1e-5).

#define NROWS 8192
#define FDIM  256
#define ODIM  256
#define NSRC  16

#define BM 32
#define BN 128
#define BK 32
#define TILES_M (NROWS / BM)   // 256 (worst case: all rows one source)
#define NTILE_N (ODIM / BN)    // 2

// ---------------------------------------------------------------------------
// Kernel 1: bucket rows by source. Single block, 1024 threads.
// ws layout: counts[16] | offsets[16] | rowidx[8192]
// ---------------------------------------------------------------------------
__global__ __launch_bounds__(1024) void bucketize_k(
        const int* __restrict__ source,
        int* __restrict__ counts,
        int* __restrict__ offsets,
        int* __restrict__ rowidx) {
    __shared__ int lcnt[NSRC];
    __shared__ int loff[NSRC];
    __shared__ int lcur[NSRC];
    const int t = threadIdx.x;
    if (t < NSRC) lcnt[t] = 0;
    __syncthreads();
    for (int i = t; i < NROWS; i += 1024) {
        atomicAdd(&lcnt[source[i]], 1);
    }
    __syncthreads();
    if (t == 0) {
        int acc = 0;
        for (int s = 0; s < NSRC; ++s) { loff[s] = acc; acc += lcnt[s]; }
    }
    __syncthreads();
    if (t < NSRC) {
        lcur[t]    = loff[t];
        counts[t]  = lcnt[t];
        offsets[t] = loff[t];
    }
    __syncthreads();
    for (int i = t; i < NROWS; i += 1024) {
        int s = source[i];
        int pos = atomicAdd(&lcur[s], 1);
        rowidx[pos] = i;
    }
}

// ---------------------------------------------------------------------------
// Kernel 2: grouped GEMM, fp32. Block = 256 threads (4 waves).
// Tile: BM=32 rows x BN=128 cols, K staged in BK=32 chunks.
// Thread grid 8x32, micro-tile 4 rows x 4 cols (float4 LDS reads).
// ---------------------------------------------------------------------------
__device__ __forceinline__ float f4get(const float4& v, int k) {
    return k == 0 ? v.x : k == 1 ? v.y : k == 2 ? v.z : v.w;
}

__global__ __launch_bounds__(256) void grouped_gemm_k(
        const float* __restrict__ x,
        const float* __restrict__ kern,
        const float* __restrict__ bias,
        const int* __restrict__ counts,
        const int* __restrict__ offsets,
        const int* __restrict__ rowidx,
        float* __restrict__ out) {
    const int s  = blockIdx.x / TILES_M;
    const int tm = blockIdx.x % TILES_M;
    const int cnt = counts[s];
    if (tm * BM >= cnt) return;                 // early-exit empty tile
    const int n0  = blockIdx.y * BN;
    const int off = offsets[s];
    const int nvalid = min(BM, cnt - tm * BM);

    __shared__ float a_lds[BM][BK];             // 32x32 fp32 = 4 KB
    __shared__ float b_lds[BK][BN];             // 32x128 fp32 = 16 KB

    const int t  = threadIdx.x;
    const int tr = t >> 5;                      // 0..7  (micro-rows tr*4..+3)
    const int tc = t & 31;                      // 0..31 (micro-cols tc*4..+3)

    // staging assignment for A (one float4 per thread): row ra, cols ca..ca+3
    const int ra = t >> 3;                      // 0..31
    const int ca = (t & 7) << 2;                // 0,4,...,28
    const int rowslot = (ra < nvalid) ? ra : 0; // duplicate row 0 for padding
    const int grow_a  = rowidx[off + tm * BM + rowslot];
    const float* xrow = x + (size_t)grow_a * FDIM;

    const size_t kb_base = ((size_t)s * FDIM) * ODIM + n0;

    float acc[4][4] = {};

    #pragma unroll
    for (int kc = 0; kc < FDIM / BK; ++kc) {
        if (kc) __syncthreads();                // previous compute done
        // stage A tile (gathered rows)
        *(float4*)&a_lds[ra][ca] = *(const float4*)&xrow[kc * BK + ca];
        // stage B tile (4 float4 per thread, coalesced along n)
        #pragma unroll
        for (int i = 0; i < 4; ++i) {
            const int kb = (t >> 5) + i * 8;    // 0..31
            const int cb = (t & 31) << 2;       // 0..124
            *(float4*)&b_lds[kb][cb] =
                *(const float4*)&kern[kb_base + (size_t)(kc * BK + kb) * ODIM + cb];
        }
        __syncthreads();
        // compute: unroll k by 4, float4 LDS reads
        #pragma unroll
        for (int k4 = 0; k4 < BK / 4; ++k4) {
            float4 av[4], bv[4];
            #pragma unroll
            for (int i = 0; i < 4; ++i)
                av[i] = *(const float4*)&a_lds[tr * 4 + i][k4 * 4];
            #pragma unroll
            for (int kk = 0; kk < 4; ++kk)
                bv[kk] = *(const float4*)&b_lds[k4 * 4 + kk][tc * 4];
            #pragma unroll
            for (int kk = 0; kk < 4; ++kk) {
                const float4 b = bv[kk];
                #pragma unroll
                for (int i = 0; i < 4; ++i) {
                    const float a = f4get(av[i], kk);
                    acc[i][0] = fmaf(a, b.x, acc[i][0]);
                    acc[i][1] = fmaf(a, b.y, acc[i][1]);
                    acc[i][2] = fmaf(a, b.z, acc[i][2]);
                    acc[i][3] = fmaf(a, b.w, acc[i][3]);
                }
            }
        }
    }

    // epilogue: add gathered bias, scatter rows back
    const float4 bv = *(const float4*)&bias[s * ODIM + n0 + tc * 4];
    #pragma unroll
    for (int i = 0; i < 4; ++i) {
        const int r = tr * 4 + i;
        if (r < nvalid) {
            const int grow = rowidx[off + tm * BM + r];
            float4 o;
            o.x = acc[i][0] + bv.x;
            o.y = acc[i][1] + bv.y;
            o.z = acc[i][2] + bv.z;
            o.w = acc[i][3] + bv.w;
            *(float4*)&out[(size_t)grow * ODIM + n0 + tc * 4] = o;
        }
    }
}

// ---------------------------------------------------------------------------
extern "C" void kernel_launch(void* const* d_in, const int* in_sizes, int n_in,
                              void* d_out, int out_size, void* d_ws, size_t ws_size,
                              hipStream_t stream) {
    const float* x      = (const float*)d_in[0];
    const int*   source = (const int*)d_in[1];   // harness passes integer inputs as int32
    const float* kern   = (const float*)d_in[2];
    const float* bias   = (const float*)d_in[3];
    float*       out    = (float*)d_out;

    int* ws      = (int*)d_ws;
    int* counts  = ws;        // 16
    int* offsets = ws + 16;   // 16
    int* rowidx  = ws + 32;   // 8192

    hipLaunchKernelGGL(bucketize_k, dim3(1), dim3(1024), 0, stream,
                       source, counts, offsets, rowidx);
    dim3 grid(NSRC * TILES_M, NTILE_N);
    hipLaunchKernelGGL(grouped_gemm_k, grid, dim3(256), 0, stream,
                       x, kern, bias, counts, offsets, rowidx, out);
}

// Round 2
// 53.883 us; speedup vs baseline: 20.5012x; 20.5012x over previous
//
#include <hip/hip_runtime.h>

// SeparateSourceDense: out[n,:] = x[n,:] @ kernel[source[n]] + bias[source[n],:]
// N=8192 rows, F=256, OUT=256, S=16 sources.
// Round 2: same bucketize + grouped fp32 GEMM, but kc loop NOT unrolled
// (#pragma unroll 1) — round 1's full unroll caused in-loop register spills
// (VGPR=256, 817 MB scratch writes, 100x write amplification, 1 ms).

#define NROWS 8192
#define FDIM  256
#define ODIM  256
#define NSRC  16

#define BM 32
#define BN 128
#define BK 32
#define TILES_M (NROWS / BM)   // 256 (worst case: all rows one source)
#define NTILE_N (ODIM / BN)    // 2

// ---------------------------------------------------------------------------
// Kernel 1: bucket rows by source. Single block, 1024 threads.
// ws layout: counts[16] | offsets[16] | rowidx[8192]
// ---------------------------------------------------------------------------
__global__ __launch_bounds__(1024) void bucketize_k(
        const int* __restrict__ source,
        int* __restrict__ counts,
        int* __restrict__ offsets,
        int* __restrict__ rowidx) {
    __shared__ int lcnt[NSRC];
    __shared__ int loff[NSRC];
    __shared__ int lcur[NSRC];
    const int t = threadIdx.x;
    if (t < NSRC) lcnt[t] = 0;
    __syncthreads();
    for (int i = t; i < NROWS; i += 1024) {
        atomicAdd(&lcnt[source[i]], 1);
    }
    __syncthreads();
    if (t == 0) {
        int acc = 0;
        for (int s = 0; s < NSRC; ++s) { loff[s] = acc; acc += lcnt[s]; }
    }
    __syncthreads();
    if (t < NSRC) {
        lcur[t]    = loff[t];
        counts[t]  = lcnt[t];
        offsets[t] = loff[t];
    }
    __syncthreads();
    for (int i = t; i < NROWS; i += 1024) {
        int s = source[i];
        int pos = atomicAdd(&lcur[s], 1);
        rowidx[pos] = i;
    }
}

// ---------------------------------------------------------------------------
// Kernel 2: grouped GEMM, fp32. Block = 256 threads (4 waves).
// Tile: BM=32 rows x BN=128 cols, K staged in BK=32 chunks.
// Thread grid 8x32, micro-tile 4 rows x 4 cols (float4 LDS reads).
// ---------------------------------------------------------------------------
__device__ __forceinline__ float f4get(const float4& v, int k) {
    return k == 0 ? v.x : k == 1 ? v.y : k == 2 ? v.z : v.w;
}

__global__ __launch_bounds__(256) void grouped_gemm_k(
        const float* __restrict__ x,
        const float* __restrict__ kern,
        const float* __restrict__ bias,
        const int* __restrict__ counts,
        const int* __restrict__ offsets,
        const int* __restrict__ rowidx,
        float* __restrict__ out) {
    const int s  = blockIdx.x / TILES_M;
    const int tm = blockIdx.x % TILES_M;
    const int cnt = counts[s];
    if (tm * BM >= cnt) return;                 // early-exit empty tile
    const int n0  = blockIdx.y * BN;
    const int off = offsets[s];
    const int nvalid = min(BM, cnt - tm * BM);

    __shared__ float a_lds[BM][BK];             // 32x32 fp32 = 4 KB
    __shared__ float b_lds[BK][BN];             // 32x128 fp32 = 16 KB

    const int t  = threadIdx.x;
    const int tr = t >> 5;                      // 0..7  (micro-rows tr*4..+3)
    const int tc = t & 31;                      // 0..31 (micro-cols tc*4..+3)

    // staging assignment for A (one float4 per thread): row ra, cols ca..ca+3
    const int ra = t >> 3;                      // 0..31
    const int ca = (t & 7) << 2;                // 0,4,...,28
    const int rowslot = (ra < nvalid) ? ra : 0; // duplicate row 0 for padding
    const int grow_a  = rowidx[off + tm * BM + rowslot];
    const float* xrow = x + (size_t)grow_a * FDIM;

    // B staging pointer: this thread's fixed (kb, cb) within the tile,
    // strided by kc * BK * ODIM each iteration.
    const int kb = t >> 5;                      // 0..7 (then +8,+16,+24)
    const int cb = (t & 31) << 2;               // 0..124
    const float* kptr = kern + ((size_t)s * FDIM) * ODIM + n0
                             + (size_t)kb * ODIM + cb;

    float acc[4][4] = {};

    #pragma unroll 1
    for (int kc = 0; kc < FDIM / BK; ++kc) {
        if (kc) __syncthreads();                // previous compute done
        // stage A tile (gathered rows)
        *(float4*)&a_lds[ra][ca] = *(const float4*)&xrow[kc * BK + ca];
        // stage B tile (4 float4 per thread, coalesced along n)
        const float* kp = kptr + (size_t)kc * BK * ODIM;
        #pragma unroll
        for (int i = 0; i < 4; ++i) {
            *(float4*)&b_lds[kb + i * 8][cb] =
                *(const float4*)&kp[(size_t)(i * 8) * ODIM];
        }
        __syncthreads();
        // compute: unroll k by 4, float4 LDS reads
        #pragma unroll
        for (int k4 = 0; k4 < BK / 4; ++k4) {
            float4 av[4], bv[4];
            #pragma unroll
            for (int i = 0; i < 4; ++i)
                av[i] = *(const float4*)&a_lds[tr * 4 + i][k4 * 4];
            #pragma unroll
            for (int kk = 0; kk < 4; ++kk)
                bv[kk] = *(const float4*)&b_lds[k4 * 4 + kk][tc * 4];
            #pragma unroll
            for (int kk = 0; kk < 4; ++kk) {
                const float4 b = bv[kk];
                #pragma unroll
                for (int i = 0; i < 4; ++i) {
                    const float a = f4get(av[i], kk);
                    acc[i][0] = fmaf(a, b.x, acc[i][0]);
                    acc[i][1] = fmaf(a, b.y, acc[i][1]);
                    acc[i][2] = fmaf(a, b.z, acc[i][2]);
                    acc[i][3] = fmaf(a, b.w, acc[i][3]);
                }
            }
        }
    }

    // epilogue: add gathered bias, scatter rows back
    const float4 bv = *(const float4*)&bias[s * ODIM + n0 + tc * 4];
    #pragma unroll
    for (int i = 0; i < 4; ++i) {
        const int r = tr * 4 + i;
        if (r < nvalid) {
            const int grow = rowidx[off + tm * BM + r];
            float4 o;
            o.x = acc[i][0] + bv.x;
            o.y = acc[i][1] + bv.y;
            o.z = acc[i][2] + bv.z;
            o.w = acc[i][3] + bv.w;
            *(float4*)&out[(size_t)grow * ODIM + n0 + tc * 4] = o;
        }
    }
}

// ---------------------------------------------------------------------------
extern "C" void kernel_launch(void* const* d_in, const int* in_sizes, int n_in,
                              void* d_out, int out_size, void* d_ws, size_t ws_size,
                              hipStream_t stream) {
    const float* x      = (const float*)d_in[0];
    const int*   source = (const int*)d_in[1];
    const float* kern   = (const float*)d_in[2];
    const float* bias   = (const float*)d_in[3];
    float*       out    = (float*)d_out;

    int* ws      = (int*)d_ws;
    int* counts  = ws;        // 16
    int* offsets = ws + 16;   // 16
    int* rowidx  = ws + 32;   // 8192

    hipLaunchKernelGGL(bucketize_k, dim3(1), dim3(1024), 0, stream,
                       source, counts, offsets, rowidx);
    dim3 grid(NSRC * TILES_M, NTILE_N);
    hipLaunchKernelGGL(grouped_gemm_k, grid, dim3(256), 0, stream,
                       x, kern, bias, counts, offsets, rowidx, out);
}

// Round 3
// 29.767 us; speedup vs baseline: 37.1108x; 1.8102x over previous
//
#include <hip/hip_runtime.h>

// SeparateSourceDense: out[n,:] = x[n,:] @ kernel[source[n]] + bias[source[n],:]
// N=8192, F=256, OUT=256, S=16.
// Round 3: bf16 MFMA grouped GEMM.
//   k1 wtrans_k:   kernel fp32 [s][f][o] -> Wt bf16 [s][o][f] (in d_ws)
//   k2 bucketize_k: counting-sort rows by source + build compact tile plan
//   k3 mfma_gemm_k: BM=64 x BN=64 tiles, full-K LDS staging (A converted
//                   fp32->bf16 in flight), 4 waves 2x2, mfma_f32_16x16x32_bf16.
// LDS row stride 264 elems (528 B): 16B-aligned for b128 ops, balanced banks.

#define NROWS 8192
#define FDIM  256
#define ODIM  256
#define NSRC  16

#define BM 64
#define BN 64
#define LDA 264
#define MAXTILES 160

// ws int32 layout: [0..15] counts | [16..31] offsets | [32] ntiles |
// [48..207] tile_s | [208..367] tile_tm | [368..8559] rowidx |
// byte offset 34240: Wt bf16 [16][256][256] (2 MB)
#define WS_NTILES   32
#define WS_TILE_S   48
#define WS_TILE_TM  208
#define WS_ROWIDX   368
#define WS_WT_INTS  8560

typedef float f32x4 __attribute__((ext_vector_type(4)));
typedef short s16x8 __attribute__((ext_vector_type(8)));

__device__ __forceinline__ uint f2bf(float f) {
    union { float f; uint u; } v; v.f = f;              // RNE, inputs are finite
    return (v.u + 0x7fffu + ((v.u >> 16) & 1u)) >> 16;
}
__device__ __forceinline__ uint pk2(float lo, float hi) {
    return f2bf(lo) | (f2bf(hi) << 16);
}

// ---------------------------------------------------------------------------
// Kernel 1: transpose+convert W[s][f][o] (fp32) -> Wt[s][o][f] (bf16)
// grid (16 sources, 16 64x64-tiles), 256 threads.
// ---------------------------------------------------------------------------
__global__ __launch_bounds__(256) void wtrans_k(const float* __restrict__ kern,
                                                ushort* __restrict__ wt) {
    __shared__ float tile[64][65];                      // stride 65: 2-way-free reads
    const int s  = blockIdx.x;
    const int fi = (blockIdx.y & 3) * 64;
    const int oi = (blockIdx.y >> 2) * 64;
    const int t  = threadIdx.x;
    const int r0 = t >> 4;                              // 0..15
    const int c4 = (t & 15) * 4;                        // 0..60
    const float* src = kern + (size_t)(s * FDIM + fi + r0) * ODIM + oi + c4;
    #pragma unroll
    for (int j = 0; j < 4; ++j) {
        const float4 v = *(const float4*)(src + (size_t)j * 16 * ODIM);
        // scalar LDS writes (stride-65 rows are not 16B-aligned for b128)
        tile[r0 + j * 16][c4 + 0] = v.x;
        tile[r0 + j * 16][c4 + 1] = v.y;
        tile[r0 + j * 16][c4 + 2] = v.z;
        tile[r0 + j * 16][c4 + 3] = v.w;
    }
    __syncthreads();
    const int f4 = (t & 15) * 4;
    #pragma unroll
    for (int j = 0; j < 4; ++j) {
        const int o_loc = (t >> 4) + j * 16;
        ushort4 u;
        u.x = (ushort)f2bf(tile[f4 + 0][o_loc]);
        u.y = (ushort)f2bf(tile[f4 + 1][o_loc]);
        u.z = (ushort)f2bf(tile[f4 + 2][o_loc]);
        u.w = (ushort)f2bf(tile[f4 + 3][o_loc]);
        *(ushort4*)&wt[(size_t)(s * ODIM + oi + o_loc) * FDIM + fi + f4] = u;
    }
}

// ---------------------------------------------------------------------------
// Kernel 2: bucket rows by source + build tile plan. 1 block, 1024 threads.
// ---------------------------------------------------------------------------
__global__ __launch_bounds__(1024) void bucketize_k(
        const int* __restrict__ source, int* __restrict__ ws) {
    __shared__ int lcnt[NSRC];
    __shared__ int loff[NSRC];
    __shared__ int lcur[NSRC];
    const int t = threadIdx.x;
    if (t < NSRC) lcnt[t] = 0;
    __syncthreads();
    for (int i = t; i < NROWS; i += 1024) atomicAdd(&lcnt[source[i]], 1);
    __syncthreads();
    if (t == 0) {
        int acc = 0;
        for (int s = 0; s < NSRC; ++s) { loff[s] = acc; acc += lcnt[s]; }
        // compact tile plan
        int nt = 0;
        for (int s = 0; s < NSRC; ++s) {
            const int ntile = (lcnt[s] + BM - 1) >> 6;
            for (int i = 0; i < ntile; ++i) {
                ws[WS_TILE_S + nt] = s;
                ws[WS_TILE_TM + nt] = i;
                ++nt;
            }
        }
        ws[WS_NTILES] = nt;
    }
    __syncthreads();
    if (t < NSRC) {
        lcur[t]     = loff[t];
        ws[t]       = lcnt[t];
        ws[16 + t]  = loff[t];
    }
    __syncthreads();
    for (int i = t; i < NROWS; i += 1024) {
        const int s = source[i];
        const int pos = atomicAdd(&lcur[s], 1);
        ws[WS_ROWIDX + pos] = i;
    }
}

// ---------------------------------------------------------------------------
// Kernel 3: MFMA grouped GEMM. 256 threads = 4 waves (2x2 of 32x32).
// ---------------------------------------------------------------------------
__global__ __launch_bounds__(256) void mfma_gemm_k(
        const float* __restrict__ x,
        const ushort* __restrict__ wt,
        const float* __restrict__ bias,
        const int* __restrict__ plan,
        float* __restrict__ out) {
    const int tile = blockIdx.x;
    if (tile >= plan[WS_NTILES]) return;
    const int s   = plan[WS_TILE_S + tile];
    const int tm  = plan[WS_TILE_TM + tile];
    const int cnt = plan[s];
    const int off = plan[16 + s];
    const int* rowidx = plan + WS_ROWIDX;
    const int n0 = blockIdx.y * BN;
    const int nvalid = min(BM, cnt - tm * BM);

    __shared__ short a_lds[BM * LDA];                   // 33 KB
    __shared__ short b_lds[BN * LDA];                   // 33 KB
    __shared__ int rows_lds[BM];

    const int t = threadIdx.x;
    if (t < BM) {
        const int slot = tm * BM + t;
        rows_lds[t] = rowidx[off + ((slot < cnt) ? slot : tm * BM)];
    }
    __syncthreads();

    // stage A: row = t>>2, elem chunks (t&3)*8 + j*32 ; fp32 -> bf16
    {
        const int ar = t >> 2;
        const int ac = (t & 3) * 8;
        const float* xrow = x + (size_t)rows_lds[ar] * FDIM + ac;
        short* dst = &a_lds[ar * LDA + ac];
        #pragma unroll
        for (int j = 0; j < 8; ++j) {
            const float4 f0 = *(const float4*)(xrow + j * 32);
            const float4 f1 = *(const float4*)(xrow + j * 32 + 4);
            uint4 p;
            p.x = pk2(f0.x, f0.y);
            p.y = pk2(f0.z, f0.w);
            p.z = pk2(f1.x, f1.y);
            p.w = pk2(f1.z, f1.w);
            *(uint4*)(dst + j * 32) = p;
        }
    }
    // stage B: n = t>>2, chunks (t&3)*8 + j*32 ; straight bf16 copy
    {
        const int br = t >> 2;
        const int bc = (t & 3) * 8;
        const ushort* wrow = wt + (size_t)(s * ODIM + n0 + br) * FDIM + bc;
        short* dst = &b_lds[br * LDA + bc];
        #pragma unroll
        for (int j = 0; j < 8; ++j) {
            *(uint4*)(dst + j * 32) = *(const uint4*)(wrow + j * 32);
        }
    }
    __syncthreads();

    const int wv = t >> 6;
    const int l  = t & 63;
    const int wr = (wv >> 1) * 32;                      // wave row offset
    const int wc = (wv & 1) * 32;                       // wave col offset
    const int lr = l & 15;
    const int lg = l >> 4;

    f32x4 acc00 = {}, acc01 = {}, acc10 = {}, acc11 = {};
    const short* ab = &a_lds[(wr + lr) * LDA + 8 * lg];
    const short* bb = &b_lds[(wc + lr) * LDA + 8 * lg];

    #pragma unroll 2
    for (int kk = 0; kk < 8; ++kk) {
        const s16x8 a0 = *(const s16x8*)(ab + kk * 32);
        const s16x8 a1 = *(const s16x8*)(ab + kk * 32 + 16 * LDA);
        const s16x8 b0 = *(const s16x8*)(bb + kk * 32);
        const s16x8 b1 = *(const s16x8*)(bb + kk * 32 + 16 * LDA);
        acc00 = __builtin_amdgcn_mfma_f32_16x16x32_bf16(a0, b0, acc00, 0, 0, 0);
        acc01 = __builtin_amdgcn_mfma_f32_16x16x32_bf16(a0, b1, acc01, 0, 0, 0);
        acc10 = __builtin_amdgcn_mfma_f32_16x16x32_bf16(a1, b0, acc10, 0, 0, 0);
        acc11 = __builtin_amdgcn_mfma_f32_16x16x32_bf16(a1, b1, acc11, 0, 0, 0);
    }

    // epilogue: D[row=4*lg+r][col=lr] per 16x16 frag; add bias, scatter rows
    const float bv0 = bias[s * ODIM + n0 + wc + lr];
    const float bv1 = bias[s * ODIM + n0 + wc + 16 + lr];
    const int col0 = n0 + wc + lr;
    #pragma unroll
    for (int r = 0; r < 4; ++r) {
        int lm = wr + 4 * lg + r;
        if (lm < nvalid) {
            float* orow = out + (size_t)rows_lds[lm] * ODIM;
            orow[col0]      = acc00[r] + bv0;
            orow[col0 + 16] = acc01[r] + bv1;
        }
        lm += 16;
        if (lm < nvalid) {
            float* orow = out + (size_t)rows_lds[lm] * ODIM;
            orow[col0]      = acc10[r] + bv0;
            orow[col0 + 16] = acc11[r] + bv1;
        }
    }
}

// ---------------------------------------------------------------------------
extern "C" void kernel_launch(void* const* d_in, const int* in_sizes, int n_in,
                              void* d_out, int out_size, void* d_ws, size_t ws_size,
                              hipStream_t stream) {
    const float* x      = (const float*)d_in[0];
    const int*   source = (const int*)d_in[1];
    const float* kern   = (const float*)d_in[2];
    const float* bias   = (const float*)d_in[3];
    float*       out    = (float*)d_out;

    int*    ws = (int*)d_ws;
    ushort* wt = (ushort*)(ws + WS_WT_INTS);

    hipLaunchKernelGGL(wtrans_k, dim3(NSRC, 16), dim3(256), 0, stream, kern, wt);
    hipLaunchKernelGGL(bucketize_k, dim3(1), dim3(1024), 0, stream, source, ws);
    hipLaunchKernelGGL(mfma_gemm_k, dim3(MAXTILES, ODIM / BN), dim3(256), 0, stream,
                       x, wt, bias, ws, out);
}